// Round 2
// baseline (2299.982 us; speedup 1.0000x reference)
//
#include <hip/hip_runtime.h>

#define TN 80000
#define HD 128
#define NE 1280000
#define NB 8
#define NPG 10000
#define NG 8000

typedef __attribute__((ext_vector_type(8))) short short8;
typedef __attribute__((ext_vector_type(4))) float f32x4;

__device__ __forceinline__ unsigned short f2bf(float f){
  unsigned int u = __float_as_uint(f);
  u = u + 0x7FFFu + ((u >> 16) & 1u);
  return (unsigned short)(u >> 16);
}

__device__ __forceinline__ short8 pack_bf8(float4 a, float4 b){
  short8 o;
  o[0] = (short)f2bf(a.x); o[1] = (short)f2bf(a.y); o[2] = (short)f2bf(a.z); o[3] = (short)f2bf(a.w);
  o[4] = (short)f2bf(b.x); o[5] = (short)f2bf(b.y); o[6] = (short)f2bf(b.z); o[7] = (short)f2bf(b.w);
  return o;
}

// Convert W_rel1 / W_root1 to bf16 (row-major [out][in])
__global__ __launch_bounds__(256) void k_conv_w(const float* __restrict__ W1, const float* __restrict__ W2,
                                                unsigned short* __restrict__ W1b, unsigned short* __restrict__ W2b){
  int i = blockIdx.x * 256 + threadIdx.x;
  W1b[i] = f2bf(W1[i]);
  W2b[i] = f2bf(W2[i]);
}

// Column sums of W_rel2 / W_root2 and sum of b_rel2
__global__ void k_colsums(const float* __restrict__ Wrel2, const float* __restrict__ Wroot2,
                          const float* __restrict__ brel2,
                          float* __restrict__ crel, float* __restrict__ croot, float* __restrict__ cb){
  int k = threadIdx.x;
  float a = 0.f, c = 0.f;
  for (int f = 0; f < HD; ++f){ a += Wrel2[f*HD + k]; c += Wroot2[f*HD + k]; }
  crel[k] = a; croot[k] = c;
  if (k == 0){ float s = 0.f; for (int f = 0; f < HD; ++f) s += brel2[f]; cb[0] = s; }
}

// Layer-1 edge scatter: z[dst] += w * x[src]   (32 threads per edge, float4 each)
__global__ __launch_bounds__(256) void k_edge1(const int* __restrict__ src, const int* __restrict__ dst,
                                               const float* __restrict__ ew, const float* __restrict__ x,
                                               float* __restrict__ z){
  long long tid = (long long)blockIdx.x * 256 + threadIdx.x;
  int e = (int)(tid >> 5);
  int c = (int)(tid & 31);
  int s = src[e];
  int d = dst[e];
  float w = ew[e];
  float4 xv = ((const float4*)x)[(size_t)s * 32 + c];
  float* zp = z + (size_t)d * HD + c * 4;
  atomicAdd(zp + 0, w * xv.x);
  atomicAdd(zp + 1, w * xv.y);
  atomicAdd(zp + 2, w * xv.z);
  atomicAdd(zp + 3, w * xv.w);
}

// Fused: h = relu(z@W1^T + x@W2^T + b); u = h . crel; v = h . croot
// One wave = 16 nodes; mfma_f32_16x16x32_bf16; h kept in registers only.
__global__ __launch_bounds__(256) void k_node(const float* __restrict__ z, const float* __restrict__ x,
    const unsigned short* __restrict__ W1b, const unsigned short* __restrict__ W2b,
    const float* __restrict__ brel1, const float* __restrict__ crel, const float* __restrict__ croot,
    float* __restrict__ u, float* __restrict__ v){
  int wid = threadIdx.x >> 6;
  int lane = threadIdx.x & 63;
  int l15 = lane & 15;
  int g4 = lane >> 4;
  int nb = blockIdx.x * 64 + wid * 16;

  const float* zrow = z + (size_t)(nb + l15) * HD + g4 * 8;
  const float* xrow = x + (size_t)(nb + l15) * HD + g4 * 8;
  short8 az[4], ax[4];
  #pragma unroll
  for (int kk = 0; kk < 4; ++kk){
    az[kk] = pack_bf8(*(const float4*)(zrow + kk * 32), *(const float4*)(zrow + kk * 32 + 4));
    ax[kk] = pack_bf8(*(const float4*)(xrow + kk * 32), *(const float4*)(xrow + kk * 32 + 4));
  }

  float usum[4] = {0,0,0,0}, vsum[4] = {0,0,0,0};
  #pragma unroll
  for (int t = 0; t < 8; ++t){
    int kcol = t * 16 + l15;                      // output feature index (C col)
    const unsigned short* w1r = W1b + (size_t)kcol * HD + g4 * 8;
    const unsigned short* w2r = W2b + (size_t)kcol * HD + g4 * 8;
    f32x4 acc = {0.f, 0.f, 0.f, 0.f};
    #pragma unroll
    for (int kk = 0; kk < 4; ++kk)
      acc = __builtin_amdgcn_mfma_f32_16x16x32_bf16(az[kk], *(const short8*)(w1r + kk * 32), acc, 0, 0, 0);
    #pragma unroll
    for (int kk = 0; kk < 4; ++kk)
      acc = __builtin_amdgcn_mfma_f32_16x16x32_bf16(ax[kk], *(const short8*)(w2r + kk * 32), acc, 0, 0, 0);
    float bias = brel1[kcol], cr = crel[kcol], co = croot[kcol];
    #pragma unroll
    for (int r = 0; r < 4; ++r){
      float h = fmaxf(acc[r] + bias, 0.f);        // C row = g4*4+r (node), col = l15 (feature)
      usum[r] += h * cr;
      vsum[r] += h * co;
    }
  }
  // reduce over the 16 feature-columns (lanes sharing g4)
  #pragma unroll
  for (int off = 1; off < 16; off <<= 1){
    #pragma unroll
    for (int r = 0; r < 4; ++r){
      usum[r] += __shfl_xor(usum[r], off);
      vsum[r] += __shfl_xor(vsum[r], off);
    }
  }
  if (l15 == 0){
    #pragma unroll
    for (int r = 0; r < 4; ++r){
      int node = nb + g4 * 4 + r;
      u[node] = usum[r];
      v[node] = vsum[r];
    }
  }
}

// Layer-2 collapsed edge scatter: s[dst] += w * u[src]  (scalar)
__global__ __launch_bounds__(256) void k_edge2(const int* __restrict__ src, const int* __restrict__ dst,
                                               const float* __restrict__ ew, const float* __restrict__ u,
                                               float* __restrict__ s){
  int e = blockIdx.x * 256 + threadIdx.x;
  atomicAdd(&s[dst[e]], ew[e] * u[src[e]]);
}

__device__ __forceinline__ float blk_red_add(float x, float* red){
  #pragma unroll
  for (int o = 32; o > 0; o >>= 1) x += __shfl_xor(x, o);
  int wid = threadIdx.x >> 6, lane = threadIdx.x & 63;
  __syncthreads();
  if (lane == 0) red[wid] = x;
  __syncthreads();
  return (red[0] + red[1]) + (red[2] + red[3]);
}
__device__ __forceinline__ float blk_red_max(float x, float* red){
  #pragma unroll
  for (int o = 32; o > 0; o >>= 1) x = fmaxf(x, __shfl_xor(x, o));
  int wid = threadIdx.x >> 6, lane = threadIdx.x & 63;
  __syncthreads();
  if (lane == 0) red[wid] = x;
  __syncthreads();
  return fmaxf(fmaxf(red[0], red[1]), fmaxf(red[2], red[3]));
}

// pooled -> LayerNorm(8000) -> log_softmax, one block per graph
__global__ __launch_bounds__(256) void k_final(const float* __restrict__ s, const float* __restrict__ vv,
    const float* __restrict__ cbp, const float* __restrict__ gamma, const float* __restrict__ beta,
    float* __restrict__ out){
  __shared__ float t[NG];
  __shared__ float red[4];
  int b = blockIdx.x, tid = threadIdx.x;
  float cb = cbp[0];
  const float inv = 1.f / (float)HD;
  float lsum = 0.f, lsq = 0.f;
  for (int j = tid; j < NG; j += 256){
    float g = (s[b*NPG + j] + vv[b*NPG + j] + cb) * inv;
    t[j] = g; lsum += g; lsq += g * g;
  }
  float S1 = blk_red_add(lsum, red);
  float S2 = blk_red_add(lsq, red);
  float mu = S1 / (float)NG;
  float var = S2 / (float)NG - mu * mu;
  float rstd = rsqrtf(var + 1e-5f);
  float lmax = -3.4e38f;
  for (int j = tid; j < NG; j += 256){
    float tj = (t[j] - mu) * rstd * gamma[j] + beta[j];
    t[j] = tj; lmax = fmaxf(lmax, tj);
  }
  float M = blk_red_max(lmax, red);
  float lexp = 0.f;
  for (int j = tid; j < NG; j += 256) lexp += expf(t[j] - M);
  float S = blk_red_add(lexp, red);
  float lse = M + logf(S);
  for (int j = tid; j < NG; j += 256) out[b*NG + j] = t[j] - lse;
}

extern "C" void kernel_launch(void* const* d_in, const int* in_sizes, int n_in,
                              void* d_out, int out_size, void* d_ws, size_t ws_size,
                              hipStream_t stream){
  const float* x      = (const float*)d_in[0];
  const int*   ei     = (const int*)d_in[1];     // int32 on device (harness converts)
  const float* ew     = (const float*)d_in[3];
  const float* Wrel1  = (const float*)d_in[4];
  const float* brel1  = (const float*)d_in[5];
  const float* Wroot1 = (const float*)d_in[6];
  const float* Wrel2  = (const float*)d_in[7];
  const float* brel2  = (const float*)d_in[8];
  const float* Wroot2 = (const float*)d_in[9];
  const float* gamma  = (const float*)d_in[10];
  const float* beta   = (const float*)d_in[11];
  const int*   src    = ei;
  const int*   dst    = ei + NE;

  char* ws = (char*)d_ws;
  size_t off = 0;
  auto alloc = [&](size_t bytes) -> char* {
    char* p = ws + off;
    off += (bytes + 511) & ~(size_t)511;
    return p;
  };
  float*          z    = (float*)alloc((size_t)TN * HD * 4);
  unsigned short* W1b  = (unsigned short*)alloc(HD * HD * 2);
  unsigned short* W2b  = (unsigned short*)alloc(HD * HD * 2);
  float*          crel = (float*)alloc(HD * 4);
  float*          croot= (float*)alloc(HD * 4);
  float*          cbp  = (float*)alloc(4);
  float*          u    = (float*)alloc(TN * 4);
  float*          v    = (float*)alloc(TN * 4);
  float*          sacc = (float*)alloc(TN * 4);

  hipMemsetAsync(z, 0, (size_t)TN * HD * 4, stream);
  hipMemsetAsync(sacc, 0, (size_t)TN * 4, stream);

  k_conv_w <<<HD*HD/256, 256, 0, stream>>>(Wrel1, Wroot1, W1b, W2b);
  k_colsums<<<1, HD, 0, stream>>>(Wrel2, Wroot2, brel2, crel, croot, cbp);
  k_edge1  <<<(NE*32)/256, 256, 0, stream>>>(src, dst, ew, x, z);
  k_node   <<<TN/64, 256, 0, stream>>>(z, x, W1b, W2b, brel1, crel, croot, u, v);
  k_edge2  <<<NE/256, 256, 0, stream>>>(src, dst, ew, u, sacc);
  k_final  <<<NB, 256, 0, stream>>>(sacc, v, cbp, gamma, beta, (float*)d_out);
}

// Round 3
// 578.995 us; speedup vs baseline: 3.9724x; 3.9724x over previous
//
#include <hip/hip_runtime.h>

#define TN 80000
#define HD 128
#define NE 1280000
#define NB 8
#define NPG 10000
#define NG 8000

typedef __attribute__((ext_vector_type(8))) short short8;
typedef __attribute__((ext_vector_type(4))) float f32x4;

__device__ __forceinline__ unsigned short f2bf(float f){
  unsigned int u = __float_as_uint(f);
  u = u + 0x7FFFu + ((u >> 16) & 1u);
  return (unsigned short)(u >> 16);
}

__device__ __forceinline__ short8 pack_bf8(float4 a, float4 b){
  short8 o;
  o[0] = (short)f2bf(a.x); o[1] = (short)f2bf(a.y); o[2] = (short)f2bf(a.z); o[3] = (short)f2bf(a.w);
  o[4] = (short)f2bf(b.x); o[5] = (short)f2bf(b.y); o[6] = (short)f2bf(b.z); o[7] = (short)f2bf(b.w);
  return o;
}

__global__ __launch_bounds__(256) void k_conv_w(const float* __restrict__ W1, const float* __restrict__ W2,
                                                unsigned short* __restrict__ W1b, unsigned short* __restrict__ W2b){
  int i = blockIdx.x * 256 + threadIdx.x;
  W1b[i] = f2bf(W1[i]);
  W2b[i] = f2bf(W2[i]);
}

__global__ void k_colsums(const float* __restrict__ Wrel2, const float* __restrict__ Wroot2,
                          const float* __restrict__ brel2,
                          float* __restrict__ crel, float* __restrict__ croot, float* __restrict__ cb){
  int k = threadIdx.x;
  float a = 0.f, c = 0.f;
  for (int f = 0; f < HD; ++f){ a += Wrel2[f*HD + k]; c += Wroot2[f*HD + k]; }
  crel[k] = a; croot[k] = c;
  if (k == 0){ float s = 0.f; for (int f = 0; f < HD; ++f) s += brel2[f]; cb[0] = s; }
}

// ---- CSR construction ----
__global__ __launch_bounds__(256) void k_hist(const int* __restrict__ dst, int* __restrict__ deg){
  int e = blockIdx.x * 256 + threadIdx.x;
  atomicAdd(&deg[dst[e]], 1);
}

// single-block exclusive scan over TN degrees -> off, cur; off[TN]=NE
__global__ __launch_bounds__(1024) void k_scan(const int* __restrict__ deg, int* __restrict__ off, int* __restrict__ cur){
  const int CH = (TN + 1023) / 1024;   // 79
  __shared__ int part[1024];
  int tid = threadIdx.x;
  int base = tid * CH;
  int s = 0;
  for (int j = 0; j < CH; ++j){ int idx = base + j; if (idx < TN) s += deg[idx]; }
  part[tid] = s;
  __syncthreads();
  int inc = s;
  for (int o = 1; o < 1024; o <<= 1){
    int t = (tid >= o) ? part[tid - o] : 0;
    __syncthreads();
    part[tid] += t;
    __syncthreads();
  }
  inc = part[tid] - s;   // exclusive prefix of this thread's chunk
  int run = inc;
  for (int j = 0; j < CH; ++j){
    int idx = base + j;
    if (idx < TN){ off[idx] = run; cur[idx] = run; run += deg[idx]; }
  }
  if (tid == 0) off[TN] = NE;
}

__global__ __launch_bounds__(256) void k_bin(const int* __restrict__ src, const int* __restrict__ dst,
                                             const float* __restrict__ ew,
                                             int* __restrict__ cur, int2* __restrict__ rec){
  int e = blockIdx.x * 256 + threadIdx.x;
  int d = dst[e];
  int p = atomicAdd(&cur[d], 1);
  rec[p] = make_int2(src[e], __float_as_int(ew[e]));
}

// ---- layer-1 aggregation: one wave per node, no atomics ----
__global__ __launch_bounds__(256) void k_gather(const int* __restrict__ off, const int2* __restrict__ rec,
                                                const float* __restrict__ x, float* __restrict__ z){
  int wid = threadIdx.x >> 6, lane = threadIdx.x & 63;
  int node = blockIdx.x * 4 + wid;
  int e0 = off[node], e1 = off[node + 1];
  const float2* xp = (const float2*)x;
  float2 acc = {0.f, 0.f};
  for (int e = e0; e < e1; ++e){
    int2 r = rec[e];                         // wave-uniform -> broadcast
    int s = r.x; float w = __int_as_float(r.y);
    float2 xv = xp[(size_t)s * 64 + lane];   // wave reads contiguous 512B row
    acc.x += w * xv.x; acc.y += w * xv.y;
  }
  ((float2*)z)[(size_t)node * 64 + lane] = acc;
}

// Fused: h = relu(z@W1^T + x@W2^T + b); u = h . crel; v = h . croot
__global__ __launch_bounds__(256) void k_node(const float* __restrict__ z, const float* __restrict__ x,
    const unsigned short* __restrict__ W1b, const unsigned short* __restrict__ W2b,
    const float* __restrict__ brel1, const float* __restrict__ crel, const float* __restrict__ croot,
    float* __restrict__ u, float* __restrict__ v){
  int wid = threadIdx.x >> 6;
  int lane = threadIdx.x & 63;
  int l15 = lane & 15;
  int g4 = lane >> 4;
  int nb = blockIdx.x * 64 + wid * 16;

  const float* zrow = z + (size_t)(nb + l15) * HD + g4 * 8;
  const float* xrow = x + (size_t)(nb + l15) * HD + g4 * 8;
  short8 az[4], ax[4];
  #pragma unroll
  for (int kk = 0; kk < 4; ++kk){
    az[kk] = pack_bf8(*(const float4*)(zrow + kk * 32), *(const float4*)(zrow + kk * 32 + 4));
    ax[kk] = pack_bf8(*(const float4*)(xrow + kk * 32), *(const float4*)(xrow + kk * 32 + 4));
  }

  float usum[4] = {0,0,0,0}, vsum[4] = {0,0,0,0};
  #pragma unroll
  for (int t = 0; t < 8; ++t){
    int kcol = t * 16 + l15;
    const unsigned short* w1r = W1b + (size_t)kcol * HD + g4 * 8;
    const unsigned short* w2r = W2b + (size_t)kcol * HD + g4 * 8;
    f32x4 acc = {0.f, 0.f, 0.f, 0.f};
    #pragma unroll
    for (int kk = 0; kk < 4; ++kk)
      acc = __builtin_amdgcn_mfma_f32_16x16x32_bf16(az[kk], *(const short8*)(w1r + kk * 32), acc, 0, 0, 0);
    #pragma unroll
    for (int kk = 0; kk < 4; ++kk)
      acc = __builtin_amdgcn_mfma_f32_16x16x32_bf16(ax[kk], *(const short8*)(w2r + kk * 32), acc, 0, 0, 0);
    float bias = brel1[kcol], cr = crel[kcol], co = croot[kcol];
    #pragma unroll
    for (int r = 0; r < 4; ++r){
      float h = fmaxf(acc[r] + bias, 0.f);
      usum[r] += h * cr;
      vsum[r] += h * co;
    }
  }
  #pragma unroll
  for (int o = 1; o < 16; o <<= 1){
    #pragma unroll
    for (int r = 0; r < 4; ++r){
      usum[r] += __shfl_xor(usum[r], o);
      vsum[r] += __shfl_xor(vsum[r], o);
    }
  }
  if (l15 == 0){
    #pragma unroll
    for (int r = 0; r < 4; ++r){
      int node = nb + g4 * 4 + r;
      u[node] = usum[r];
      v[node] = vsum[r];
    }
  }
}

// ---- layer-2 collapsed aggregation via CSR: thread per node, no atomics ----
__global__ __launch_bounds__(256) void k_pool2(const int* __restrict__ off, const int2* __restrict__ rec,
                                               const float* __restrict__ u, float* __restrict__ sacc){
  int i = blockIdx.x * 256 + threadIdx.x;
  if (i >= TN) return;
  int e0 = off[i], e1 = off[i + 1];
  float s = 0.f;
  for (int e = e0; e < e1; ++e){
    int2 r = rec[e];
    s += __int_as_float(r.y) * u[r.x];
  }
  sacc[i] = s;
}

__device__ __forceinline__ float blk_red_add(float x, float* red){
  #pragma unroll
  for (int o = 32; o > 0; o >>= 1) x += __shfl_xor(x, o);
  int wid = threadIdx.x >> 6, lane = threadIdx.x & 63;
  __syncthreads();
  if (lane == 0) red[wid] = x;
  __syncthreads();
  return (red[0] + red[1]) + (red[2] + red[3]);
}
__device__ __forceinline__ float blk_red_max(float x, float* red){
  #pragma unroll
  for (int o = 32; o > 0; o >>= 1) x = fmaxf(x, __shfl_xor(x, o));
  int wid = threadIdx.x >> 6, lane = threadIdx.x & 63;
  __syncthreads();
  if (lane == 0) red[wid] = x;
  __syncthreads();
  return fmaxf(fmaxf(red[0], red[1]), fmaxf(red[2], red[3]));
}

__global__ __launch_bounds__(256) void k_final(const float* __restrict__ s, const float* __restrict__ vv,
    const float* __restrict__ cbp, const float* __restrict__ gamma, const float* __restrict__ beta,
    float* __restrict__ out){
  __shared__ float t[NG];
  __shared__ float red[4];
  int b = blockIdx.x, tid = threadIdx.x;
  float cb = cbp[0];
  const float inv = 1.f / (float)HD;
  float lsum = 0.f, lsq = 0.f;
  for (int j = tid; j < NG; j += 256){
    float g = (s[b*NPG + j] + vv[b*NPG + j] + cb) * inv;
    t[j] = g; lsum += g; lsq += g * g;
  }
  float S1 = blk_red_add(lsum, red);
  float S2 = blk_red_add(lsq, red);
  float mu = S1 / (float)NG;
  float var = S2 / (float)NG - mu * mu;
  float rstd = rsqrtf(var + 1e-5f);
  float lmax = -3.4e38f;
  for (int j = tid; j < NG; j += 256){
    float tj = (t[j] - mu) * rstd * gamma[j] + beta[j];
    t[j] = tj; lmax = fmaxf(lmax, tj);
  }
  float M = blk_red_max(lmax, red);
  float lexp = 0.f;
  for (int j = tid; j < NG; j += 256) lexp += expf(t[j] - M);
  float S = blk_red_add(lexp, red);
  float lse = M + logf(S);
  for (int j = tid; j < NG; j += 256) out[b*NG + j] = t[j] - lse;
}

extern "C" void kernel_launch(void* const* d_in, const int* in_sizes, int n_in,
                              void* d_out, int out_size, void* d_ws, size_t ws_size,
                              hipStream_t stream){
  const float* x      = (const float*)d_in[0];
  const int*   ei     = (const int*)d_in[1];
  const float* ew     = (const float*)d_in[3];
  const float* Wrel1  = (const float*)d_in[4];
  const float* brel1  = (const float*)d_in[5];
  const float* Wroot1 = (const float*)d_in[6];
  const float* Wrel2  = (const float*)d_in[7];
  const float* brel2  = (const float*)d_in[8];
  const float* Wroot2 = (const float*)d_in[9];
  const float* gamma  = (const float*)d_in[10];
  const float* beta   = (const float*)d_in[11];
  const int*   src    = ei;
  const int*   dst    = ei + NE;

  char* ws = (char*)d_ws;
  size_t off_b = 0;
  auto alloc = [&](size_t bytes) -> char* {
    char* p = ws + off_b;
    off_b += (bytes + 511) & ~(size_t)511;
    return p;
  };
  float*          z    = (float*)alloc((size_t)TN * HD * 4);
  unsigned short* W1b  = (unsigned short*)alloc(HD * HD * 2);
  unsigned short* W2b  = (unsigned short*)alloc(HD * HD * 2);
  float*          crel = (float*)alloc(HD * 4);
  float*          croot= (float*)alloc(HD * 4);
  float*          cbp  = (float*)alloc(4);
  float*          u    = (float*)alloc(TN * 4);
  float*          v    = (float*)alloc(TN * 4);
  float*          sacc = (float*)alloc(TN * 4);
  int*            deg  = (int*)alloc(TN * 4);
  int*            offp = (int*)alloc((TN + 1) * 4);
  int*            cur  = (int*)alloc(TN * 4);
  int2*           rec  = (int2*)alloc((size_t)NE * 8);

  hipMemsetAsync(deg, 0, TN * 4, stream);

  k_conv_w <<<HD*HD/256, 256, 0, stream>>>(Wrel1, Wroot1, W1b, W2b);
  k_colsums<<<1, HD, 0, stream>>>(Wrel2, Wroot2, brel2, crel, croot, cbp);
  k_hist   <<<NE/256, 256, 0, stream>>>(dst, deg);
  k_scan   <<<1, 1024, 0, stream>>>(deg, offp, cur);
  k_bin    <<<NE/256, 256, 0, stream>>>(src, dst, ew, cur, rec);
  k_gather <<<TN/4, 256, 0, stream>>>(offp, rec, x, z);
  k_node   <<<TN/64, 256, 0, stream>>>(z, x, W1b, W2b, brel1, crel, croot, u, v);
  k_pool2  <<<(TN+255)/256, 256, 0, stream>>>(offp, rec, u, sacc);
  k_final  <<<NB, 256, 0, stream>>>(sacc, v, cbp, gamma, beta, (float*)d_out);
}

// Round 4
// 384.151 us; speedup vs baseline: 5.9872x; 1.5072x over previous
//
#include <hip/hip_runtime.h>

#define TN 80000
#define HD 128
#define NE 1280000
#define NB 8
#define NPG 10000
#define NG 8000
#define NBLK ((TN + 255) / 256)   // 313

typedef __attribute__((ext_vector_type(8))) short short8;
typedef __attribute__((ext_vector_type(4))) float f32x4;

__device__ __forceinline__ unsigned short f2bf(float f){
  unsigned int u = __float_as_uint(f);
  u = u + 0x7FFFu + ((u >> 16) & 1u);
  return (unsigned short)(u >> 16);
}

__device__ __forceinline__ short8 pack_bf8(float4 a, float4 b){
  short8 o;
  o[0] = (short)f2bf(a.x); o[1] = (short)f2bf(a.y); o[2] = (short)f2bf(a.z); o[3] = (short)f2bf(a.w);
  o[4] = (short)f2bf(b.x); o[5] = (short)f2bf(b.y); o[6] = (short)f2bf(b.z); o[7] = (short)f2bf(b.w);
  return o;
}

__global__ __launch_bounds__(256) void k_conv_w(const float* __restrict__ W1, const float* __restrict__ W2,
                                                unsigned short* __restrict__ W1b, unsigned short* __restrict__ W2b){
  int i = blockIdx.x * 256 + threadIdx.x;
  W1b[i] = f2bf(W1[i]);
  W2b[i] = f2bf(W2[i]);
}

__global__ void k_colsums(const float* __restrict__ Wrel2, const float* __restrict__ Wroot2,
                          const float* __restrict__ brel2,
                          float* __restrict__ crel, float* __restrict__ croot, float* __restrict__ cb){
  int k = threadIdx.x;
  float a = 0.f, c = 0.f;
  for (int f = 0; f < HD; ++f){ a += Wrel2[f*HD + k]; c += Wroot2[f*HD + k]; }
  crel[k] = a; croot[k] = c;
  if (k == 0){ float s = 0.f; for (int f = 0; f < HD; ++f) s += brel2[f]; cb[0] = s; }
}

// ---- CSR construction ----
__global__ __launch_bounds__(256) void k_hist(const int* __restrict__ dst, int* __restrict__ deg){
  int e = blockIdx.x * 256 + threadIdx.x;
  atomicAdd(&deg[dst[e]], 1);
}

// hierarchical scan, stage 1: per-block sums
__global__ __launch_bounds__(256) void k_scan_part(const int* __restrict__ deg, int* __restrict__ bsum){
  __shared__ int ws[4];
  int t = threadIdx.x;
  int i = blockIdx.x * 256 + t;
  int v = (i < TN) ? deg[i] : 0;
  #pragma unroll
  for (int o = 32; o > 0; o >>= 1) v += __shfl_xor(v, o);
  if ((t & 63) == 0) ws[t >> 6] = v;
  __syncthreads();
  if (t == 0) bsum[blockIdx.x] = (ws[0] + ws[1]) + (ws[2] + ws[3]);
}

// stage 2: exclusive scan of 313 block sums (in place), one block
__global__ __launch_bounds__(512) void k_scan_mid(int* __restrict__ bsum){
  __shared__ int sh[512];
  int t = threadIdx.x;
  int v = (t < NBLK) ? bsum[t] : 0;
  sh[t] = v;
  __syncthreads();
  for (int o = 1; o < 512; o <<= 1){
    int u = (t >= o) ? sh[t - o] : 0;
    __syncthreads();
    sh[t] += u;
    __syncthreads();
  }
  if (t < NBLK) bsum[t] = sh[t] - v;   // exclusive
}

// stage 3: block-local exclusive scan + block offset -> off, cur
__global__ __launch_bounds__(256) void k_scan_fin(const int* __restrict__ deg, const int* __restrict__ bsum,
                                                  int* __restrict__ off, int* __restrict__ cur){
  __shared__ int wsum[4];
  int t = threadIdx.x, lane = t & 63, w = t >> 6;
  int i = blockIdx.x * 256 + t;
  int d = (i < TN) ? deg[i] : 0;
  int v = d;
  #pragma unroll
  for (int o = 1; o < 64; o <<= 1){ int u = __shfl_up(v, o); if (lane >= o) v += u; }
  if (lane == 63) wsum[w] = v;
  __syncthreads();
  int woff = 0;
  for (int j = 0; j < w; ++j) woff += wsum[j];
  int excl = bsum[blockIdx.x] + woff + v - d;
  if (i < TN){ off[i] = excl; cur[i] = excl; }
  if (i == 0) off[TN] = NE;
}

__global__ __launch_bounds__(256) void k_bin(const int* __restrict__ src, const int* __restrict__ dst,
                                             const float* __restrict__ ew,
                                             int* __restrict__ cur, int2* __restrict__ rec){
  int e = blockIdx.x * 256 + threadIdx.x;
  int d = dst[e];
  int p = atomicAdd(&cur[d], 1);
  rec[p] = make_int2(src[e], __float_as_int(ew[e]));
}

// ---- layer-1 aggregation: one wave per node, no atomics ----
__global__ __launch_bounds__(256) void k_gather(const int* __restrict__ off, const int2* __restrict__ rec,
                                                const float* __restrict__ x, float* __restrict__ z){
  int wid = threadIdx.x >> 6, lane = threadIdx.x & 63;
  int node = blockIdx.x * 4 + wid;
  int e0 = off[node], e1 = off[node + 1];
  const float2* xp = (const float2*)x;
  float2 acc = {0.f, 0.f};
  for (int e = e0; e < e1; ++e){
    int2 r = rec[e];                         // wave-uniform -> broadcast
    int s = r.x; float w = __int_as_float(r.y);
    float2 xv = xp[(size_t)s * 64 + lane];   // wave reads contiguous 512B row
    acc.x += w * xv.x; acc.y += w * xv.y;
  }
  ((float2*)z)[(size_t)node * 64 + lane] = acc;
}

// Fused: h = relu(z@W1^T + x@W2^T + b); u = h . crel; v = h . croot
__global__ __launch_bounds__(256) void k_node(const float* __restrict__ z, const float* __restrict__ x,
    const unsigned short* __restrict__ W1b, const unsigned short* __restrict__ W2b,
    const float* __restrict__ brel1, const float* __restrict__ crel, const float* __restrict__ croot,
    float* __restrict__ u, float* __restrict__ v){
  int wid = threadIdx.x >> 6;
  int lane = threadIdx.x & 63;
  int l15 = lane & 15;
  int g4 = lane >> 4;
  int nb = blockIdx.x * 64 + wid * 16;

  const float* zrow = z + (size_t)(nb + l15) * HD + g4 * 8;
  const float* xrow = x + (size_t)(nb + l15) * HD + g4 * 8;
  short8 az[4], ax[4];
  #pragma unroll
  for (int kk = 0; kk < 4; ++kk){
    az[kk] = pack_bf8(*(const float4*)(zrow + kk * 32), *(const float4*)(zrow + kk * 32 + 4));
    ax[kk] = pack_bf8(*(const float4*)(xrow + kk * 32), *(const float4*)(xrow + kk * 32 + 4));
  }

  float usum[4] = {0,0,0,0}, vsum[4] = {0,0,0,0};
  #pragma unroll
  for (int t = 0; t < 8; ++t){
    int kcol = t * 16 + l15;
    const unsigned short* w1r = W1b + (size_t)kcol * HD + g4 * 8;
    const unsigned short* w2r = W2b + (size_t)kcol * HD + g4 * 8;
    f32x4 acc = {0.f, 0.f, 0.f, 0.f};
    #pragma unroll
    for (int kk = 0; kk < 4; ++kk)
      acc = __builtin_amdgcn_mfma_f32_16x16x32_bf16(az[kk], *(const short8*)(w1r + kk * 32), acc, 0, 0, 0);
    #pragma unroll
    for (int kk = 0; kk < 4; ++kk)
      acc = __builtin_amdgcn_mfma_f32_16x16x32_bf16(ax[kk], *(const short8*)(w2r + kk * 32), acc, 0, 0, 0);
    float bias = brel1[kcol], cr = crel[kcol], co = croot[kcol];
    #pragma unroll
    for (int r = 0; r < 4; ++r){
      float h = fmaxf(acc[r] + bias, 0.f);
      usum[r] += h * cr;
      vsum[r] += h * co;
    }
  }
  #pragma unroll
  for (int o = 1; o < 16; o <<= 1){
    #pragma unroll
    for (int r = 0; r < 4; ++r){
      usum[r] += __shfl_xor(usum[r], o);
      vsum[r] += __shfl_xor(vsum[r], o);
    }
  }
  if (l15 == 0){
    #pragma unroll
    for (int r = 0; r < 4; ++r){
      int node = nb + g4 * 4 + r;
      u[node] = usum[r];
      v[node] = vsum[r];
    }
  }
}

// ---- layer-2 collapsed aggregation via CSR: thread per node, no atomics ----
__global__ __launch_bounds__(256) void k_pool2(const int* __restrict__ off, const int2* __restrict__ rec,
                                               const float* __restrict__ u, float* __restrict__ sacc){
  int i = blockIdx.x * 256 + threadIdx.x;
  if (i >= TN) return;
  int e0 = off[i], e1 = off[i + 1];
  float s = 0.f;
  for (int e = e0; e < e1; ++e){
    int2 r = rec[e];
    s += __int_as_float(r.y) * u[r.x];
  }
  sacc[i] = s;
}

__device__ __forceinline__ float blk_red_add(float x, float* red){
  #pragma unroll
  for (int o = 32; o > 0; o >>= 1) x += __shfl_xor(x, o);
  int wid = threadIdx.x >> 6, lane = threadIdx.x & 63;
  __syncthreads();
  if (lane == 0) red[wid] = x;
  __syncthreads();
  return (red[0] + red[1]) + (red[2] + red[3]);
}
__device__ __forceinline__ float blk_red_max(float x, float* red){
  #pragma unroll
  for (int o = 32; o > 0; o >>= 1) x = fmaxf(x, __shfl_xor(x, o));
  int wid = threadIdx.x >> 6, lane = threadIdx.x & 63;
  __syncthreads();
  if (lane == 0) red[wid] = x;
  __syncthreads();
  return fmaxf(fmaxf(red[0], red[1]), fmaxf(red[2], red[3]));
}

__global__ __launch_bounds__(256) void k_final(const float* __restrict__ s, const float* __restrict__ vv,
    const float* __restrict__ cbp, const float* __restrict__ gamma, const float* __restrict__ beta,
    float* __restrict__ out){
  __shared__ float t[NG];
  __shared__ float red[4];
  int b = blockIdx.x, tid = threadIdx.x;
  float cb = cbp[0];
  const float inv = 1.f / (float)HD;
  float lsum = 0.f, lsq = 0.f;
  for (int j = tid; j < NG; j += 256){
    float g = (s[b*NPG + j] + vv[b*NPG + j] + cb) * inv;
    t[j] = g; lsum += g; lsq += g * g;
  }
  float S1 = blk_red_add(lsum, red);
  float S2 = blk_red_add(lsq, red);
  float mu = S1 / (float)NG;
  float var = S2 / (float)NG - mu * mu;
  float rstd = rsqrtf(var + 1e-5f);
  float lmax = -3.4e38f;
  for (int j = tid; j < NG; j += 256){
    float tj = (t[j] - mu) * rstd * gamma[j] + beta[j];
    t[j] = tj; lmax = fmaxf(lmax, tj);
  }
  float M = blk_red_max(lmax, red);
  float lexp = 0.f;
  for (int j = tid; j < NG; j += 256) lexp += expf(t[j] - M);
  float S = blk_red_add(lexp, red);
  float lse = M + logf(S);
  for (int j = tid; j < NG; j += 256) out[b*NG + j] = t[j] - lse;
}

extern "C" void kernel_launch(void* const* d_in, const int* in_sizes, int n_in,
                              void* d_out, int out_size, void* d_ws, size_t ws_size,
                              hipStream_t stream){
  const float* x      = (const float*)d_in[0];
  const int*   ei     = (const int*)d_in[1];
  const float* ew     = (const float*)d_in[3];
  const float* Wrel1  = (const float*)d_in[4];
  const float* brel1  = (const float*)d_in[5];
  const float* Wroot1 = (const float*)d_in[6];
  const float* Wrel2  = (const float*)d_in[7];
  const float* brel2  = (const float*)d_in[8];
  const float* Wroot2 = (const float*)d_in[9];
  const float* gamma  = (const float*)d_in[10];
  const float* beta   = (const float*)d_in[11];
  const int*   src    = ei;
  const int*   dst    = ei + NE;

  char* ws = (char*)d_ws;
  size_t off_b = 0;
  auto alloc = [&](size_t bytes) -> char* {
    char* p = ws + off_b;
    off_b += (bytes + 511) & ~(size_t)511;
    return p;
  };
  float*          z    = (float*)alloc((size_t)TN * HD * 4);
  unsigned short* W1b  = (unsigned short*)alloc(HD * HD * 2);
  unsigned short* W2b  = (unsigned short*)alloc(HD * HD * 2);
  float*          crel = (float*)alloc(HD * 4);
  float*          croot= (float*)alloc(HD * 4);
  float*          cbp  = (float*)alloc(4);
  float*          u    = (float*)alloc(TN * 4);
  float*          v    = (float*)alloc(TN * 4);
  float*          sacc = (float*)alloc(TN * 4);
  int*            deg  = (int*)alloc(TN * 4);
  int*            offp = (int*)alloc((TN + 1) * 4);
  int*            cur  = (int*)alloc(TN * 4);
  int*            bsum = (int*)alloc(NBLK * 4);
  int2*           rec  = (int2*)alloc((size_t)NE * 8);

  hipMemsetAsync(deg, 0, TN * 4, stream);

  k_conv_w   <<<HD*HD/256, 256, 0, stream>>>(Wrel1, Wroot1, W1b, W2b);
  k_colsums  <<<1, HD, 0, stream>>>(Wrel2, Wroot2, brel2, crel, croot, cbp);
  k_hist     <<<NE/256, 256, 0, stream>>>(dst, deg);
  k_scan_part<<<NBLK, 256, 0, stream>>>(deg, bsum);
  k_scan_mid <<<1, 512, 0, stream>>>(bsum);
  k_scan_fin <<<NBLK, 256, 0, stream>>>(deg, bsum, offp, cur);
  k_bin      <<<NE/256, 256, 0, stream>>>(src, dst, ew, cur, rec);
  k_gather   <<<TN/4, 256, 0, stream>>>(offp, rec, x, z);
  k_node     <<<TN/64, 256, 0, stream>>>(z, x, W1b, W2b, brel1, crel, croot, u, v);
  k_pool2    <<<(TN+255)/256, 256, 0, stream>>>(offp, rec, u, sacc);
  k_final    <<<NB, 256, 0, stream>>>(sacc, v, cbp, gamma, beta, (float*)d_out);
}

// Round 5
// 374.585 us; speedup vs baseline: 6.1401x; 1.0255x over previous
//
#include <hip/hip_runtime.h>

#define TN 80000
#define HD 128
#define NE 1280000
#define NB 8
#define NPG 10000
#define NG 8000
#define NBLK ((TN + 255) / 256)   // 313

typedef __attribute__((ext_vector_type(8))) short short8;
typedef __attribute__((ext_vector_type(4))) float f32x4;

__device__ __forceinline__ unsigned short f2bf(float f){
  unsigned int u = __float_as_uint(f);
  u = u + 0x7FFFu + ((u >> 16) & 1u);
  return (unsigned short)(u >> 16);
}

__device__ __forceinline__ short8 pack_bf8(float4 a, float4 b){
  short8 o;
  o[0] = (short)f2bf(a.x); o[1] = (short)f2bf(a.y); o[2] = (short)f2bf(a.z); o[3] = (short)f2bf(a.w);
  o[4] = (short)f2bf(b.x); o[5] = (short)f2bf(b.y); o[6] = (short)f2bf(b.z); o[7] = (short)f2bf(b.w);
  return o;
}

__global__ __launch_bounds__(256) void k_conv_w(const float* __restrict__ W1, const float* __restrict__ W2,
                                                unsigned short* __restrict__ W1b, unsigned short* __restrict__ W2b){
  int i = blockIdx.x * 256 + threadIdx.x;
  W1b[i] = f2bf(W1[i]);
  W2b[i] = f2bf(W2[i]);
}

// x (f32) -> xb (bf16), 8 elems/thread
__global__ __launch_bounds__(256) void k_convx(const float* __restrict__ x, unsigned short* __restrict__ xb){
  size_t i = ((size_t)blockIdx.x * 256 + threadIdx.x) * 8;
  float4 a0 = *(const float4*)(x + i), a1 = *(const float4*)(x + i + 4);
  *(short8*)(xb + i) = pack_bf8(a0, a1);
}

__global__ void k_colsums(const float* __restrict__ Wrel2, const float* __restrict__ Wroot2,
                          const float* __restrict__ brel2,
                          float* __restrict__ crel, float* __restrict__ croot, float* __restrict__ cb){
  int k = threadIdx.x;
  float a = 0.f, c = 0.f;
  for (int f = 0; f < HD; ++f){ a += Wrel2[f*HD + k]; c += Wroot2[f*HD + k]; }
  crel[k] = a; croot[k] = c;
  if (k == 0){ float s = 0.f; for (int f = 0; f < HD; ++f) s += brel2[f]; cb[0] = s; }
}

// ---- CSR construction ----
__global__ __launch_bounds__(256) void k_hist(const int* __restrict__ dst, int* __restrict__ deg){
  int e = blockIdx.x * 256 + threadIdx.x;
  atomicAdd(&deg[dst[e]], 1);
}

__global__ __launch_bounds__(256) void k_scan_part(const int* __restrict__ deg, int* __restrict__ bsum){
  __shared__ int ws[4];
  int t = threadIdx.x;
  int i = blockIdx.x * 256 + t;
  int v = (i < TN) ? deg[i] : 0;
  #pragma unroll
  for (int o = 32; o > 0; o >>= 1) v += __shfl_xor(v, o);
  if ((t & 63) == 0) ws[t >> 6] = v;
  __syncthreads();
  if (t == 0) bsum[blockIdx.x] = (ws[0] + ws[1]) + (ws[2] + ws[3]);
}

__global__ __launch_bounds__(512) void k_scan_mid(int* __restrict__ bsum){
  __shared__ int sh[512];
  int t = threadIdx.x;
  int v = (t < NBLK) ? bsum[t] : 0;
  sh[t] = v;
  __syncthreads();
  for (int o = 1; o < 512; o <<= 1){
    int u = (t >= o) ? sh[t - o] : 0;
    __syncthreads();
    sh[t] += u;
    __syncthreads();
  }
  if (t < NBLK) bsum[t] = sh[t] - v;   // exclusive
}

__global__ __launch_bounds__(256) void k_scan_fin(const int* __restrict__ deg, const int* __restrict__ bsum,
                                                  int* __restrict__ off, int* __restrict__ cur){
  __shared__ int wsum[4];
  int t = threadIdx.x, lane = t & 63, w = t >> 6;
  int i = blockIdx.x * 256 + t;
  int d = (i < TN) ? deg[i] : 0;
  int v = d;
  #pragma unroll
  for (int o = 1; o < 64; o <<= 1){ int u = __shfl_up(v, o); if (lane >= o) v += u; }
  if (lane == 63) wsum[w] = v;
  __syncthreads();
  int woff = 0;
  for (int j = 0; j < w; ++j) woff += wsum[j];
  int excl = bsum[blockIdx.x] + woff + v - d;
  if (i < TN){ off[i] = excl; cur[i] = excl; }
  if (i == 0) off[TN] = NE;
}

__global__ __launch_bounds__(256) void k_bin(const int* __restrict__ src, const int* __restrict__ dst,
                                             const float* __restrict__ ew,
                                             int* __restrict__ cur, int2* __restrict__ rec){
  int e = blockIdx.x * 256 + threadIdx.x;
  int d = dst[e];
  int p = atomicAdd(&cur[d], 1);
  rec[p] = make_int2(src[e], __float_as_int(ew[e]));
}

// ---- layer-1 aggregation: one wave per node, bf16 gather, f32 accum, bf16 z ----
__global__ __launch_bounds__(256) void k_gather(const int* __restrict__ off, const int2* __restrict__ rec,
                                                const unsigned short* __restrict__ xb, unsigned short* __restrict__ zb){
  int wid = threadIdx.x >> 6, lane = threadIdx.x & 63;
  int node = blockIdx.x * 4 + wid;
  int e0 = off[node], e1 = off[node + 1];
  const unsigned int* xp = (const unsigned int*)xb;
  float ax = 0.f, ay = 0.f;
  for (int e = e0; e < e1; ++e){
    int2 r = rec[e];                            // wave-uniform -> broadcast
    float w = __int_as_float(r.y);
    unsigned int p = xp[(size_t)r.x * 64 + lane]; // 2 bf16, wave reads 256B row
    float lo = __uint_as_float(p << 16);
    float hi = __uint_as_float(p & 0xFFFF0000u);
    ax += w * lo; ay += w * hi;
  }
  unsigned int o = ((unsigned int)f2bf(ay) << 16) | (unsigned int)f2bf(ax);
  ((unsigned int*)zb)[(size_t)node * 64 + lane] = o;
}

// Fused: h = relu(z@W1^T + x@W2^T + b); u = h . crel; v = h . croot  (bf16 inputs)
__global__ __launch_bounds__(256) void k_node(const unsigned short* __restrict__ zb, const unsigned short* __restrict__ xb,
    const unsigned short* __restrict__ W1b, const unsigned short* __restrict__ W2b,
    const float* __restrict__ brel1, const float* __restrict__ crel, const float* __restrict__ croot,
    float* __restrict__ u, float* __restrict__ v){
  int wid = threadIdx.x >> 6;
  int lane = threadIdx.x & 63;
  int l15 = lane & 15;
  int g4 = lane >> 4;
  int nb = blockIdx.x * 64 + wid * 16;

  const unsigned short* zrow = zb + (size_t)(nb + l15) * HD + g4 * 8;
  const unsigned short* xrow = xb + (size_t)(nb + l15) * HD + g4 * 8;
  short8 az[4], ax[4];
  #pragma unroll
  for (int kk = 0; kk < 4; ++kk){
    az[kk] = *(const short8*)(zrow + kk * 32);
    ax[kk] = *(const short8*)(xrow + kk * 32);
  }

  float usum[4] = {0,0,0,0}, vsum[4] = {0,0,0,0};
  #pragma unroll
  for (int t = 0; t < 8; ++t){
    int kcol = t * 16 + l15;
    const unsigned short* w1r = W1b + (size_t)kcol * HD + g4 * 8;
    const unsigned short* w2r = W2b + (size_t)kcol * HD + g4 * 8;
    f32x4 acc = {0.f, 0.f, 0.f, 0.f};
    #pragma unroll
    for (int kk = 0; kk < 4; ++kk)
      acc = __builtin_amdgcn_mfma_f32_16x16x32_bf16(az[kk], *(const short8*)(w1r + kk * 32), acc, 0, 0, 0);
    #pragma unroll
    for (int kk = 0; kk < 4; ++kk)
      acc = __builtin_amdgcn_mfma_f32_16x16x32_bf16(ax[kk], *(const short8*)(w2r + kk * 32), acc, 0, 0, 0);
    float bias = brel1[kcol], cr = crel[kcol], co = croot[kcol];
    #pragma unroll
    for (int r = 0; r < 4; ++r){
      float h = fmaxf(acc[r] + bias, 0.f);
      usum[r] += h * cr;
      vsum[r] += h * co;
    }
  }
  #pragma unroll
  for (int o = 1; o < 16; o <<= 1){
    #pragma unroll
    for (int r = 0; r < 4; ++r){
      usum[r] += __shfl_xor(usum[r], o);
      vsum[r] += __shfl_xor(vsum[r], o);
    }
  }
  if (l15 == 0){
    #pragma unroll
    for (int r = 0; r < 4; ++r){
      int node = nb + g4 * 4 + r;
      u[node] = usum[r];
      v[node] = vsum[r];
    }
  }
}

// ---- layer-2 collapsed aggregation via CSR ----
__global__ __launch_bounds__(256) void k_pool2(const int* __restrict__ off, const int2* __restrict__ rec,
                                               const float* __restrict__ u, float* __restrict__ sacc){
  int i = blockIdx.x * 256 + threadIdx.x;
  if (i >= TN) return;
  int e0 = off[i], e1 = off[i + 1];
  float s = 0.f;
  for (int e = e0; e < e1; ++e){
    int2 r = rec[e];
    s += __int_as_float(r.y) * u[r.x];
  }
  sacc[i] = s;
}

__device__ __forceinline__ float blk_red_add(float x, float* red){
  #pragma unroll
  for (int o = 32; o > 0; o >>= 1) x += __shfl_xor(x, o);
  int wid = threadIdx.x >> 6, lane = threadIdx.x & 63;
  __syncthreads();
  if (lane == 0) red[wid] = x;
  __syncthreads();
  return (red[0] + red[1]) + (red[2] + red[3]);
}
__device__ __forceinline__ float blk_red_max(float x, float* red){
  #pragma unroll
  for (int o = 32; o > 0; o >>= 1) x = fmaxf(x, __shfl_xor(x, o));
  int wid = threadIdx.x >> 6, lane = threadIdx.x & 63;
  __syncthreads();
  if (lane == 0) red[wid] = x;
  __syncthreads();
  return fmaxf(fmaxf(red[0], red[1]), fmaxf(red[2], red[3]));
}

__global__ __launch_bounds__(256) void k_final(const float* __restrict__ s, const float* __restrict__ vv,
    const float* __restrict__ cbp, const float* __restrict__ gamma, const float* __restrict__ beta,
    float* __restrict__ out){
  __shared__ float t[NG];
  __shared__ float red[4];
  int b = blockIdx.x, tid = threadIdx.x;
  float cb = cbp[0];
  const float inv = 1.f / (float)HD;
  float lsum = 0.f, lsq = 0.f;
  for (int j = tid; j < NG; j += 256){
    float g = (s[b*NPG + j] + vv[b*NPG + j] + cb) * inv;
    t[j] = g; lsum += g; lsq += g * g;
  }
  float S1 = blk_red_add(lsum, red);
  float S2 = blk_red_add(lsq, red);
  float mu = S1 / (float)NG;
  float var = S2 / (float)NG - mu * mu;
  float rstd = rsqrtf(var + 1e-5f);
  float lmax = -3.4e38f;
  for (int j = tid; j < NG; j += 256){
    float tj = (t[j] - mu) * rstd * gamma[j] + beta[j];
    t[j] = tj; lmax = fmaxf(lmax, tj);
  }
  float M = blk_red_max(lmax, red);
  float lexp = 0.f;
  for (int j = tid; j < NG; j += 256) lexp += expf(t[j] - M);
  float S = blk_red_add(lexp, red);
  float lse = M + logf(S);
  for (int j = tid; j < NG; j += 256) out[b*NG + j] = t[j] - lse;
}

extern "C" void kernel_launch(void* const* d_in, const int* in_sizes, int n_in,
                              void* d_out, int out_size, void* d_ws, size_t ws_size,
                              hipStream_t stream){
  const float* x      = (const float*)d_in[0];
  const int*   ei     = (const int*)d_in[1];
  const float* ew     = (const float*)d_in[3];
  const float* Wrel1  = (const float*)d_in[4];
  const float* brel1  = (const float*)d_in[5];
  const float* Wroot1 = (const float*)d_in[6];
  const float* Wrel2  = (const float*)d_in[7];
  const float* brel2  = (const float*)d_in[8];
  const float* Wroot2 = (const float*)d_in[9];
  const float* gamma  = (const float*)d_in[10];
  const float* beta   = (const float*)d_in[11];
  const int*   src    = ei;
  const int*   dst    = ei + NE;

  char* ws = (char*)d_ws;
  size_t off_b = 0;
  auto alloc = [&](size_t bytes) -> char* {
    char* p = ws + off_b;
    off_b += (bytes + 511) & ~(size_t)511;
    return p;
  };
  unsigned short* xb   = (unsigned short*)alloc((size_t)TN * HD * 2);
  unsigned short* zb   = (unsigned short*)alloc((size_t)TN * HD * 2);
  unsigned short* W1b  = (unsigned short*)alloc(HD * HD * 2);
  unsigned short* W2b  = (unsigned short*)alloc(HD * HD * 2);
  float*          crel = (float*)alloc(HD * 4);
  float*          croot= (float*)alloc(HD * 4);
  float*          cbp  = (float*)alloc(4);
  float*          u    = (float*)alloc(TN * 4);
  float*          v    = (float*)alloc(TN * 4);
  float*          sacc = (float*)alloc(TN * 4);
  int*            deg  = (int*)alloc(TN * 4);
  int*            offp = (int*)alloc((TN + 1) * 4);
  int*            cur  = (int*)alloc(TN * 4);
  int*            bsum = (int*)alloc(NBLK * 4);
  int2*           rec  = (int2*)alloc((size_t)NE * 8);

  hipMemsetAsync(deg, 0, TN * 4, stream);

  k_conv_w   <<<HD*HD/256, 256, 0, stream>>>(Wrel1, Wroot1, W1b, W2b);
  k_convx    <<<(TN*HD/8)/256, 256, 0, stream>>>(x, xb);
  k_colsums  <<<1, HD, 0, stream>>>(Wrel2, Wroot2, brel2, crel, croot, cbp);
  k_hist     <<<NE/256, 256, 0, stream>>>(dst, deg);
  k_scan_part<<<NBLK, 256, 0, stream>>>(deg, bsum);
  k_scan_mid <<<1, 512, 0, stream>>>(bsum);
  k_scan_fin <<<NBLK, 256, 0, stream>>>(deg, bsum, offp, cur);
  k_bin      <<<NE/256, 256, 0, stream>>>(src, dst, ew, cur, rec);
  k_gather   <<<TN/4, 256, 0, stream>>>(offp, rec, xb, zb);
  k_node     <<<TN/64, 256, 0, stream>>>(zb, xb, W1b, W2b, brel1, crel, croot, u, v);
  k_pool2    <<<(TN+255)/256, 256, 0, stream>>>(offp, rec, u, sacc);
  k_final    <<<NB, 256, 0, stream>>>(sacc, v, cbp, gamma, beta, (float*)d_out);
}

// Round 6
// 303.065 us; speedup vs baseline: 7.5891x; 1.2360x over previous
//
#include <hip/hip_runtime.h>

#define TN 80000
#define HD 128
#define NE 1280000
#define NB 8
#define NPG 10000
#define NG 8000
#define NBLK ((TN + 255) / 256)   // 313

typedef __attribute__((ext_vector_type(8))) short short8;
typedef __attribute__((ext_vector_type(4))) float f32x4;

__device__ __forceinline__ unsigned short f2bf(float f){
  unsigned int u = __float_as_uint(f);
  u = u + 0x7FFFu + ((u >> 16) & 1u);
  return (unsigned short)(u >> 16);
}

__device__ __forceinline__ short8 pack_bf8(float4 a, float4 b){
  short8 o;
  o[0] = (short)f2bf(a.x); o[1] = (short)f2bf(a.y); o[2] = (short)f2bf(a.z); o[3] = (short)f2bf(a.w);
  o[4] = (short)f2bf(b.x); o[5] = (short)f2bf(b.y); o[6] = (short)f2bf(b.z); o[7] = (short)f2bf(b.w);
  return o;
}

__global__ __launch_bounds__(256) void k_conv_w(const float* __restrict__ W1, const float* __restrict__ W2,
                                                unsigned short* __restrict__ W1b, unsigned short* __restrict__ W2b){
  int i = blockIdx.x * 256 + threadIdx.x;
  W1b[i] = f2bf(W1[i]);
  W2b[i] = f2bf(W2[i]);
}

// x (f32) -> xb (bf16), 8 elems/thread
__global__ __launch_bounds__(256) void k_convx(const float* __restrict__ x, unsigned short* __restrict__ xb){
  size_t i = ((size_t)blockIdx.x * 256 + threadIdx.x) * 8;
  float4 a0 = *(const float4*)(x + i), a1 = *(const float4*)(x + i + 4);
  *(short8*)(xb + i) = pack_bf8(a0, a1);
}

__global__ void k_colsums(const float* __restrict__ Wrel2, const float* __restrict__ Wroot2,
                          const float* __restrict__ brel2,
                          float* __restrict__ crel, float* __restrict__ croot, float* __restrict__ cb){
  int k = threadIdx.x;
  float a = 0.f, c = 0.f;
  for (int f = 0; f < HD; ++f){ a += Wrel2[f*HD + k]; c += Wroot2[f*HD + k]; }
  crel[k] = a; croot[k] = c;
  if (k == 0){ float s = 0.f; for (int f = 0; f < HD; ++f) s += brel2[f]; cb[0] = s; }
}

// ---- CSR construction ----
__global__ __launch_bounds__(256) void k_hist(const int* __restrict__ dst, int* __restrict__ deg){
  int e = blockIdx.x * 256 + threadIdx.x;
  atomicAdd(&deg[dst[e]], 1);
}

__global__ __launch_bounds__(256) void k_scan_part(const int* __restrict__ deg, int* __restrict__ bsum){
  __shared__ int ws[4];
  int t = threadIdx.x;
  int i = blockIdx.x * 256 + t;
  int v = (i < TN) ? deg[i] : 0;
  #pragma unroll
  for (int o = 32; o > 0; o >>= 1) v += __shfl_xor(v, o);
  if ((t & 63) == 0) ws[t >> 6] = v;
  __syncthreads();
  if (t == 0) bsum[blockIdx.x] = (ws[0] + ws[1]) + (ws[2] + ws[3]);
}

__global__ __launch_bounds__(512) void k_scan_mid(int* __restrict__ bsum){
  __shared__ int sh[512];
  int t = threadIdx.x;
  int v = (t < NBLK) ? bsum[t] : 0;
  sh[t] = v;
  __syncthreads();
  for (int o = 1; o < 512; o <<= 1){
    int u = (t >= o) ? sh[t - o] : 0;
    __syncthreads();
    sh[t] += u;
    __syncthreads();
  }
  if (t < NBLK) bsum[t] = sh[t] - v;   // exclusive
}

__global__ __launch_bounds__(256) void k_scan_fin(const int* __restrict__ deg, const int* __restrict__ bsum,
                                                  int* __restrict__ off, int* __restrict__ cur){
  __shared__ int wsum[4];
  int t = threadIdx.x, lane = t & 63, w = t >> 6;
  int i = blockIdx.x * 256 + t;
  int d = (i < TN) ? deg[i] : 0;
  int v = d;
  #pragma unroll
  for (int o = 1; o < 64; o <<= 1){ int u = __shfl_up(v, o); if (lane >= o) v += u; }
  if (lane == 63) wsum[w] = v;
  __syncthreads();
  int woff = 0;
  for (int j = 0; j < w; ++j) woff += wsum[j];
  int excl = bsum[blockIdx.x] + woff + v - d;
  if (i < TN){ off[i] = excl; cur[i] = excl; }
  if (i == 0) off[TN] = NE;
}

__global__ __launch_bounds__(256) void k_bin(const int* __restrict__ src, const int* __restrict__ dst,
                                             const float* __restrict__ ew,
                                             int* __restrict__ cur, int2* __restrict__ rec){
  int e = blockIdx.x * 256 + threadIdx.x;
  int d = dst[e];
  int p = atomicAdd(&cur[d], 1);
  rec[p] = make_int2(src[e], __float_as_int(ew[e]));
}

// ---- layer-1 aggregation: one wave per node, 4 edges/step, 2-deep pipeline ----
// lanes split into 4 groups of 16; group g handles edge e+g, each lane loads
// 16B (8 bf16) of the 256B row -> one dwordx4 per 4 edges.
__global__ __launch_bounds__(256) void k_gather(const int* __restrict__ off, const int2* __restrict__ rec,
                                                const unsigned short* __restrict__ xb, unsigned short* __restrict__ zb){
  int wid = threadIdx.x >> 6, lane = threadIdx.x & 63;
  int node = blockIdx.x * 4 + wid;
  int e0 = off[node], e1 = off[node + 1];
  int g  = lane >> 4;     // edge group 0..3
  int sl = lane & 15;     // 16B slot within row
  const uint4* xp = (const uint4*)xb;   // row = 16 uint4

  float acc[8] = {0,0,0,0,0,0,0,0};

  #define GSTEP(EBASE)                                                        \
  {                                                                           \
    int ee = (EBASE) + g;                                                     \
    bool val = ee < e1;                                                       \
    int2 r = rec[val ? ee : e1 - 1];                                          \
    float w = val ? __int_as_float(r.y) : 0.f;                                \
    uint4 p = xp[(size_t)r.x * 16 + sl];                                      \
    acc[0] += w * __uint_as_float(p.x << 16);                                 \
    acc[1] += w * __uint_as_float(p.x & 0xFFFF0000u);                         \
    acc[2] += w * __uint_as_float(p.y << 16);                                 \
    acc[3] += w * __uint_as_float(p.y & 0xFFFF0000u);                         \
    acc[4] += w * __uint_as_float(p.z << 16);                                 \
    acc[5] += w * __uint_as_float(p.z & 0xFFFF0000u);                         \
    acc[6] += w * __uint_as_float(p.w << 16);                                 \
    acc[7] += w * __uint_as_float(p.w & 0xFFFF0000u);                         \
  }

  int e = e0;
  for (; e + 8 <= e1; e += 8){   // 8 edges in flight (2 chunks of 4)
    GSTEP(e)
    GSTEP(e + 4)
  }
  if (e < e1){ GSTEP(e) if (e + 4 < e1){ GSTEP(e + 4) } }
  #undef GSTEP

  // combine the 4 edge-groups: sum over lanes differing in bits 4,5
  #pragma unroll
  for (int o = 16; o <= 32; o <<= 1){
    #pragma unroll
    for (int i = 0; i < 8; ++i) acc[i] += __shfl_xor(acc[i], o);
  }
  if (g == 0){
    uint4 o4;
    o4.x = ((unsigned)f2bf(acc[1]) << 16) | (unsigned)f2bf(acc[0]);
    o4.y = ((unsigned)f2bf(acc[3]) << 16) | (unsigned)f2bf(acc[2]);
    o4.z = ((unsigned)f2bf(acc[5]) << 16) | (unsigned)f2bf(acc[4]);
    o4.w = ((unsigned)f2bf(acc[7]) << 16) | (unsigned)f2bf(acc[6]);
    ((uint4*)zb)[(size_t)node * 16 + sl] = o4;
  }
}

// Fused: h = relu(z@W1^T + x@W2^T + b); u = h . crel; v = h . croot  (bf16 inputs)
__global__ __launch_bounds__(256) void k_node(const unsigned short* __restrict__ zb, const unsigned short* __restrict__ xb,
    const unsigned short* __restrict__ W1b, const unsigned short* __restrict__ W2b,
    const float* __restrict__ brel1, const float* __restrict__ crel, const float* __restrict__ croot,
    float* __restrict__ u, float* __restrict__ v){
  int wid = threadIdx.x >> 6;
  int lane = threadIdx.x & 63;
  int l15 = lane & 15;
  int g4 = lane >> 4;
  int nb = blockIdx.x * 64 + wid * 16;

  const unsigned short* zrow = zb + (size_t)(nb + l15) * HD + g4 * 8;
  const unsigned short* xrow = xb + (size_t)(nb + l15) * HD + g4 * 8;
  short8 az[4], ax[4];
  #pragma unroll
  for (int kk = 0; kk < 4; ++kk){
    az[kk] = *(const short8*)(zrow + kk * 32);
    ax[kk] = *(const short8*)(xrow + kk * 32);
  }

  float usum[4] = {0,0,0,0}, vsum[4] = {0,0,0,0};
  #pragma unroll
  for (int t = 0; t < 8; ++t){
    int kcol = t * 16 + l15;
    const unsigned short* w1r = W1b + (size_t)kcol * HD + g4 * 8;
    const unsigned short* w2r = W2b + (size_t)kcol * HD + g4 * 8;
    f32x4 acc = {0.f, 0.f, 0.f, 0.f};
    #pragma unroll
    for (int kk = 0; kk < 4; ++kk)
      acc = __builtin_amdgcn_mfma_f32_16x16x32_bf16(az[kk], *(const short8*)(w1r + kk * 32), acc, 0, 0, 0);
    #pragma unroll
    for (int kk = 0; kk < 4; ++kk)
      acc = __builtin_amdgcn_mfma_f32_16x16x32_bf16(ax[kk], *(const short8*)(w2r + kk * 32), acc, 0, 0, 0);
    float bias = brel1[kcol], cr = crel[kcol], co = croot[kcol];
    #pragma unroll
    for (int r = 0; r < 4; ++r){
      float h = fmaxf(acc[r] + bias, 0.f);
      usum[r] += h * cr;
      vsum[r] += h * co;
    }
  }
  #pragma unroll
  for (int o = 1; o < 16; o <<= 1){
    #pragma unroll
    for (int r = 0; r < 4; ++r){
      usum[r] += __shfl_xor(usum[r], o);
      vsum[r] += __shfl_xor(vsum[r], o);
    }
  }
  if (l15 == 0){
    #pragma unroll
    for (int r = 0; r < 4; ++r){
      int node = nb + g4 * 4 + r;
      u[node] = usum[r];
      v[node] = vsum[r];
    }
  }
}

// ---- layer-2 collapsed aggregation via CSR ----
__global__ __launch_bounds__(256) void k_pool2(const int* __restrict__ off, const int2* __restrict__ rec,
                                               const float* __restrict__ u, float* __restrict__ sacc){
  int i = blockIdx.x * 256 + threadIdx.x;
  if (i >= TN) return;
  int e0 = off[i], e1 = off[i + 1];
  float s = 0.f;
  for (int e = e0; e < e1; ++e){
    int2 r = rec[e];
    s += __int_as_float(r.y) * u[r.x];
  }
  sacc[i] = s;
}

__device__ __forceinline__ float blk_red_add(float x, float* red){
  #pragma unroll
  for (int o = 32; o > 0; o >>= 1) x += __shfl_xor(x, o);
  int wid = threadIdx.x >> 6, lane = threadIdx.x & 63;
  __syncthreads();
  if (lane == 0) red[wid] = x;
  __syncthreads();
  return (red[0] + red[1]) + (red[2] + red[3]);
}
__device__ __forceinline__ float blk_red_max(float x, float* red){
  #pragma unroll
  for (int o = 32; o > 0; o >>= 1) x = fmaxf(x, __shfl_xor(x, o));
  int wid = threadIdx.x >> 6, lane = threadIdx.x & 63;
  __syncthreads();
  if (lane == 0) red[wid] = x;
  __syncthreads();
  return fmaxf(fmaxf(red[0], red[1]), fmaxf(red[2], red[3]));
}

__global__ __launch_bounds__(256) void k_final(const float* __restrict__ s, const float* __restrict__ vv,
    const float* __restrict__ cbp, const float* __restrict__ gamma, const float* __restrict__ beta,
    float* __restrict__ out){
  __shared__ float t[NG];
  __shared__ float red[4];
  int b = blockIdx.x, tid = threadIdx.x;
  float cb = cbp[0];
  const float inv = 1.f / (float)HD;
  float lsum = 0.f, lsq = 0.f;
  for (int j = tid; j < NG; j += 256){
    float g = (s[b*NPG + j] + vv[b*NPG + j] + cb) * inv;
    t[j] = g; lsum += g; lsq += g * g;
  }
  float S1 = blk_red_add(lsum, red);
  float S2 = blk_red_add(lsq, red);
  float mu = S1 / (float)NG;
  float var = S2 / (float)NG - mu * mu;
  float rstd = rsqrtf(var + 1e-5f);
  float lmax = -3.4e38f;
  for (int j = tid; j < NG; j += 256){
    float tj = (t[j] - mu) * rstd * gamma[j] + beta[j];
    t[j] = tj; lmax = fmaxf(lmax, tj);
  }
  float M = blk_red_max(lmax, red);
  float lexp = 0.f;
  for (int j = tid; j < NG; j += 256) lexp += expf(t[j] - M);
  float S = blk_red_add(lexp, red);
  float lse = M + logf(S);
  for (int j = tid; j < NG; j += 256) out[b*NG + j] = t[j] - lse;
}

extern "C" void kernel_launch(void* const* d_in, const int* in_sizes, int n_in,
                              void* d_out, int out_size, void* d_ws, size_t ws_size,
                              hipStream_t stream){
  const float* x      = (const float*)d_in[0];
  const int*   ei     = (const int*)d_in[1];
  const float* ew     = (const float*)d_in[3];
  const float* Wrel1  = (const float*)d_in[4];
  const float* brel1  = (const float*)d_in[5];
  const float* Wroot1 = (const float*)d_in[6];
  const float* Wrel2  = (const float*)d_in[7];
  const float* brel2  = (const float*)d_in[8];
  const float* Wroot2 = (const float*)d_in[9];
  const float* gamma  = (const float*)d_in[10];
  const float* beta   = (const float*)d_in[11];
  const int*   src    = ei;
  const int*   dst    = ei + NE;

  char* ws = (char*)d_ws;
  size_t off_b = 0;
  auto alloc = [&](size_t bytes) -> char* {
    char* p = ws + off_b;
    off_b += (bytes + 511) & ~(size_t)511;
    return p;
  };
  unsigned short* xb   = (unsigned short*)alloc((size_t)TN * HD * 2);
  unsigned short* zb   = (unsigned short*)alloc((size_t)TN * HD * 2);
  unsigned short* W1b  = (unsigned short*)alloc(HD * HD * 2);
  unsigned short* W2b  = (unsigned short*)alloc(HD * HD * 2);
  float*          crel = (float*)alloc(HD * 4);
  float*          croot= (float*)alloc(HD * 4);
  float*          cbp  = (float*)alloc(4);
  float*          u    = (float*)alloc(TN * 4);
  float*          v    = (float*)alloc(TN * 4);
  float*          sacc = (float*)alloc(TN * 4);
  int*            deg  = (int*)alloc(TN * 4);
  int*            offp = (int*)alloc((TN + 1) * 4);
  int*            cur  = (int*)alloc(TN * 4);
  int*            bsum = (int*)alloc(NBLK * 4);
  int2*           rec  = (int2*)alloc((size_t)NE * 8);

  hipMemsetAsync(deg, 0, TN * 4, stream);

  k_conv_w   <<<HD*HD/256, 256, 0, stream>>>(Wrel1, Wroot1, W1b, W2b);
  k_convx    <<<(TN*HD/8)/256, 256, 0, stream>>>(x, xb);
  k_colsums  <<<1, HD, 0, stream>>>(Wrel2, Wroot2, brel2, crel, croot, cbp);
  k_hist     <<<NE/256, 256, 0, stream>>>(dst, deg);
  k_scan_part<<<NBLK, 256, 0, stream>>>(deg, bsum);
  k_scan_mid <<<1, 512, 0, stream>>>(bsum);
  k_scan_fin <<<NBLK, 256, 0, stream>>>(deg, bsum, offp, cur);
  k_bin      <<<NE/256, 256, 0, stream>>>(src, dst, ew, cur, rec);
  k_gather   <<<TN/4, 256, 0, stream>>>(offp, rec, xb, zb);
  k_node     <<<TN/64, 256, 0, stream>>>(zb, xb, W1b, W2b, brel1, crel, croot, u, v);
  k_pool2    <<<(TN+255)/256, 256, 0, stream>>>(offp, rec, u, sacc);
  k_final    <<<NB, 256, 0, stream>>>(sacc, v, cbp, gamma, beta, (float*)d_out);
}